// Round 2
// baseline (268.601 us; speedup 1.0000x reference)
//
#include <hip/hip_runtime.h>

// NTN: out[n,k] = relu( cos(x1 @ W1[k], x2 @ W2[k]) + [x1,x2]·V[k] + b[k] )
// N=32768, D=128, K=16.
// R2 structure:
//  - prep: W1,W2 -> bf16 MFMA A-fragments (W^T, M=e). Chunk cc=k*2+h (32KB) holds
//    BOTH sides for e-group h (et = h*4+et', et' 0..3): unit
//    (side*1024 + et'*256 + s*64 + lane). V -> bf16 A-fragments.
//  - main: grid 512 = (rb 0..127) x (kh 0..3). Block: 256 thr / 4 waves,
//    256 rows/block, 64 rows/wave (nt=4 tiles of 16), k range [4kh, 4kh+4).
//    X fragments (B-operand, k-invariant) in registers (128 VGPR).
//    Per k: two 32KB chunks ping-pong via global_load_lds; per (et',nt) compute
//    T1/T2 tiles back-to-back (both sides resident) and fold into nm/q1/q2 --
//    no acc1 array. e-reduction: in-lane FMAs + shfl_xor(16)+shfl_xor(32).
//    part2+b kept in registers (accP); epilogue is a single predicated scalar
//    store per (k, nt) -- zero in-loop global RMW.

typedef __attribute__((ext_vector_type(8))) __bf16 bf16x8;
typedef __attribute__((ext_vector_type(8))) unsigned short us8;
typedef __attribute__((ext_vector_type(4))) float f32x4;

static __device__ __forceinline__ unsigned short f2bf(float f) {
  unsigned u = __float_as_uint(f);
  u += 0x7FFFu + ((u >> 16) & 1u);   // round-to-nearest-even
  return (unsigned short)(u >> 16);
}

static __device__ __forceinline__ bf16x8 as_bf(us8 u) {
  bf16x8 r;
  __builtin_memcpy(&r, &u, sizeof(r));
  return r;
}

// ---------------- prep ----------------
// wsW: 32 chunks (cc = k*2 + h) of 2048 16B-units.
//   unit u: side=(u>>10)&1, et'=(u>>8)&3, s=(u>>6)&3, lane=u&63.
//   frag[j] = W_side[k][d = s*32 + (lane>>4)*8 + j][e = (h*4+et')*16 + (lane&15)]
// wsV: unit cs*64+lane: frag[j] = V[lane&15][c = cs*32 + (lane>>4)*8 + j]
__global__ void ntn_prep(const float* __restrict__ W1, const float* __restrict__ W2,
                         const float* __restrict__ V,
                         unsigned short* __restrict__ wsW, unsigned short* __restrict__ wsV) {
  int t = blockIdx.x * 256 + threadIdx.x;
  if (t < 65536) {
    int u = t & 2047;
    int lane = u & 63, s = (u >> 6) & 3, et2 = (u >> 8) & 3, side = (u >> 10) & 1;
    int cc = t >> 11, h = cc & 1, k = cc >> 1;
    int q = lane >> 4, l15 = lane & 15;
    int et = h * 4 + et2;
    const float* W = side ? W2 : W1;
    const float* src = W + k * 16384 + (s * 32 + q * 8) * 128 + (et * 16 + l15);
    us8 r;
#pragma unroll
    for (int j = 0; j < 8; ++j) r[j] = f2bf(src[j * 128]);
    *(us8*)(wsW + (size_t)t * 8) = r;
  } else if (t < 66048) {
    int u = t - 65536;
    int lane = u & 63, cs = u >> 6;
    int q = lane >> 4, l15 = lane & 15;
    const float* src = V + l15 * 256 + cs * 32 + q * 8;
    us8 r;
#pragma unroll
    for (int j = 0; j < 8; ++j) r[j] = f2bf(src[j]);
    *(us8*)(wsV + (size_t)u * 8) = r;
  }
}

// ---------------- main ----------------
__global__ __launch_bounds__(256, 2) void ntn_main(
    const float* __restrict__ x1, const float* __restrict__ x2,
    const float* __restrict__ b,
    const unsigned short* __restrict__ wsW, const unsigned short* __restrict__ wsV,
    float* __restrict__ out) {
  __shared__ uint4 ldsW[2][2048];   // two 32KB chunk slots = 64KB

  const int tid = threadIdx.x;
  const int lane = tid & 63, wave = tid >> 6;
  const int q = lane >> 4, l15 = lane & 15;
  const int kh = blockIdx.x & 3;          // k range [4kh, 4kh+4)
  const int rb = blockIdx.x >> 2;         // 256-row group
  const int rowbase = rb * 256 + wave * 64;

  const f32x4 zero4 = {0.f, 0.f, 0.f, 0.f};

  // async stage of one 32KB chunk into an LDS slot (8 glds x 64 lanes x 16B / wave)
  auto stage = [&](int cc, int slot) {
    const unsigned short* src = wsW + (size_t)cc * 16384 + (size_t)(wave * 512 + lane) * 8;
    uint4* dst = &ldsW[slot][wave * 512];
#pragma unroll
    for (int i = 0; i < 8; ++i)
      __builtin_amdgcn_global_load_lds(
          (__attribute__((address_space(1))) void*)(void*)(src + i * 512),
          (__attribute__((address_space(3))) void*)(dst + i * 64), 16, 0, 0);
  };

  stage(kh * 8 + 0, 0);   // first chunk of our k range

  // ---- X fragments (B-operand), bf16, k-invariant, in registers ----
  // frag[j] = X[row = rowbase + nt*16 + (lane&15)][d = s*32 + (lane>>4)*8 + j]
  bf16x8 xb[2][4][4];
#pragma unroll
  for (int side = 0; side < 2; ++side) {
    const float* xp0 = side ? x2 : x1;
#pragma unroll
    for (int nt = 0; nt < 4; ++nt) {
#pragma unroll
      for (int s = 0; s < 4; ++s) {
        const float* p = xp0 + (size_t)(rowbase + nt * 16 + l15) * 128 + s * 32 + q * 8;
        float4 v0 = *(const float4*)p;
        float4 v1 = *(const float4*)(p + 4);
        us8 uu;
        uu[0] = f2bf(v0.x); uu[1] = f2bf(v0.y); uu[2] = f2bf(v0.z); uu[3] = f2bf(v0.w);
        uu[4] = f2bf(v1.x); uu[5] = f2bf(v1.y); uu[6] = f2bf(v1.z); uu[7] = f2bf(v1.w);
        xb[side][nt][s] = as_bf(uu);
      }
    }
  }

  // ---- part2 + b via MFMA (A = V frags: M=k; B = X frags), kept in registers ----
  f32x4 accP[4];
  {
    bf16x8 vf[8];
#pragma unroll
    for (int cs = 0; cs < 8; ++cs)
      vf[cs] = as_bf(*(const us8*)(wsV + (size_t)(cs * 64 + lane) * 8));
    float4 bv = *(const float4*)(b + q * 4);
#pragma unroll
    for (int nt = 0; nt < 4; ++nt) {
      f32x4 a = zero4;
#pragma unroll
      for (int cs = 0; cs < 8; ++cs)
        a = __builtin_amdgcn_mfma_f32_16x16x32_bf16(vf[cs], xb[cs >> 2][nt][cs & 3], a, 0, 0, 0);
      a.x += bv.x; a.y += bv.y; a.z += bv.z; a.w += bv.w;
      accP[nt] = a;   // lane q holds part2+b for k = q*4 + reg; only q==kh used
    }
  }

  float nm[4] = {0.f, 0.f, 0.f, 0.f};
  float q1[4] = {0.f, 0.f, 0.f, 0.f};
  float q2[4] = {0.f, 0.f, 0.f, 0.f};

  // compute one e-group (4 e-tiles, both sides) from an LDS slot, fold reductions
  auto compute = [&](int slot) {
#pragma unroll
    for (int et = 0; et < 4; ++et) {
      bf16x8 wa[4], wb[4];
#pragma unroll
      for (int s = 0; s < 4; ++s) {
        wa[s] = as_bf(*(const us8*)&ldsW[slot][et * 256 + s * 64 + lane]);
        wb[s] = as_bf(*(const us8*)&ldsW[slot][1024 + et * 256 + s * 64 + lane]);
      }
#pragma unroll
      for (int nt = 0; nt < 4; ++nt) {
        f32x4 a1 = zero4, a2 = zero4;
#pragma unroll
        for (int s = 0; s < 4; ++s)
          a1 = __builtin_amdgcn_mfma_f32_16x16x32_bf16(wa[s], xb[0][nt][s], a1, 0, 0, 0);
#pragma unroll
        for (int s = 0; s < 4; ++s)
          a2 = __builtin_amdgcn_mfma_f32_16x16x32_bf16(wb[s], xb[1][nt][s], a2, 0, 0, 0);
        nm[nt] += a1.x * a2.x + a1.y * a2.y + a1.z * a2.z + a1.w * a2.w;
        q1[nt] += a1.x * a1.x + a1.y * a1.y + a1.z * a1.z + a1.w * a1.w;
        q2[nt] += a2.x * a2.x + a2.y * a2.y + a2.z * a2.z + a2.w * a2.w;
      }
    }
  };

#pragma unroll 1
  for (int kk = 0; kk < 4; ++kk) {
    const int cbase = kh * 8 + 2 * kk;
    __syncthreads();                       // chunk (kk, h=0) in slot0; slot1 free
    stage(cbase + 1, 1);
    compute(0);
    __syncthreads();                       // chunk (kk, h=1) in slot1; slot0 free
    if (kk < 3) stage(cbase + 2, 0);
    compute(1);

    const int k = kh * 4 + kk;
#pragma unroll
    for (int nt = 0; nt < 4; ++nt) {
      float n = nm[nt], s1 = q1[nt], s2 = q2[nt];
      n  += __shfl_xor(n, 16);  n  += __shfl_xor(n, 32);
      s1 += __shfl_xor(s1, 16); s1 += __shfl_xor(s1, 32);
      s2 += __shfl_xor(s2, 16); s2 += __shfl_xor(s2, 32);
      float d1 = fmaxf(sqrtf(s1), 1e-8f);
      float d2 = fmaxf(sqrtf(s2), 1e-8f);
      float p1 = n / (d1 * d2);
      float pc = (kk == 0) ? accP[nt].x : (kk == 1) ? accP[nt].y
               : (kk == 2) ? accP[nt].z : accP[nt].w;
      if (q == kh)
        out[(size_t)(rowbase + nt * 16 + l15) * 16 + k] = fmaxf(p1 + pc, 0.f);
      nm[nt] = 0.f; q1[nt] = 0.f; q2[nt] = 0.f;
    }
  }
}

extern "C" void kernel_launch(void* const* d_in, const int* in_sizes, int n_in,
                              void* d_out, int out_size, void* d_ws, size_t ws_size,
                              hipStream_t stream) {
  const float* x1 = (const float*)d_in[0];
  const float* x2 = (const float*)d_in[1];
  const float* W1 = (const float*)d_in[2];
  const float* W2 = (const float*)d_in[3];
  const float* V  = (const float*)d_in[4];
  const float* b  = (const float*)d_in[5];
  float* out = (float*)d_out;
  unsigned short* wsW = (unsigned short*)d_ws;
  unsigned short* wsV = wsW + (size_t)65536 * 8;   // 1MB offset

  ntn_prep<<<258, 256, 0, stream>>>(W1, W2, V, wsW, wsV);
  ntn_main<<<512, 256, 0, stream>>>(x1, x2, b, wsW, wsV, out);
}

// Round 3
// 120.593 us; speedup vs baseline: 2.2273x; 2.2273x over previous
//
#include <hip/hip_runtime.h>

// NTN: out[n,k] = relu( cos(x1 @ W1[k], x2 @ W2[k]) + [x1,x2]·V[k] + b[k] )
// N=32768, D=128, K=16.
// R3 structure (R1 per-wave shape + R2's chunk layout, occupancy via k-split):
//  - prep: W1,W2 -> bf16 MFMA A-fragments (W^T, M=e). Chunk cc=k*2+h (32KB)
//    holds BOTH sides for e-half h. V -> bf16 A-fragments.
//  - main: grid 512 = (rb 0..255) x (kh 0..1). Block: 256 thr / 4 waves,
//    128 rows/block, 32 rows/wave (nt=2 -> xb = 64 VGPRs, total ~150, no spill).
//    2 blocks/CU (LDS 64KB each) -> 8 waves/CU; independent blocks overlap
//    each other's barrier drains. k range [8kh, 8kh+8).
//    Per k: two 32KB chunks ping-pong via global_load_lds; per (et',nt) T1/T2
//    computed back-to-back and folded into nm/q1/q2 (no acc1 array).
//    e-reduction: in-lane FMAs + shfl_xor(16)+shfl_xor(32).
//    part2+b in registers (accP); epilogue = predicated scalar store per (k,nt).

typedef __attribute__((ext_vector_type(8))) __bf16 bf16x8;
typedef __attribute__((ext_vector_type(8))) unsigned short us8;
typedef __attribute__((ext_vector_type(4))) float f32x4;

static __device__ __forceinline__ unsigned short f2bf(float f) {
  unsigned u = __float_as_uint(f);
  u += 0x7FFFu + ((u >> 16) & 1u);   // round-to-nearest-even
  return (unsigned short)(u >> 16);
}

static __device__ __forceinline__ bf16x8 as_bf(us8 u) {
  bf16x8 r;
  __builtin_memcpy(&r, &u, sizeof(r));
  return r;
}

// ---------------- prep ----------------
// wsW: 32 chunks (cc = k*2 + h) of 2048 16B-units.
//   unit u: side=(u>>10)&1, et'=(u>>8)&3, s=(u>>6)&3, lane=u&63.
//   frag[j] = W_side[k][d = s*32 + (lane>>4)*8 + j][e = (h*4+et')*16 + (lane&15)]
// wsV: unit cs*64+lane: frag[j] = V[lane&15][c = cs*32 + (lane>>4)*8 + j]
__global__ void ntn_prep(const float* __restrict__ W1, const float* __restrict__ W2,
                         const float* __restrict__ V,
                         unsigned short* __restrict__ wsW, unsigned short* __restrict__ wsV) {
  int t = blockIdx.x * 256 + threadIdx.x;
  if (t < 65536) {
    int u = t & 2047;
    int lane = u & 63, s = (u >> 6) & 3, et2 = (u >> 8) & 3, side = (u >> 10) & 1;
    int cc = t >> 11, h = cc & 1, k = cc >> 1;
    int q = lane >> 4, l15 = lane & 15;
    int et = h * 4 + et2;
    const float* W = side ? W2 : W1;
    const float* src = W + k * 16384 + (s * 32 + q * 8) * 128 + (et * 16 + l15);
    us8 r;
#pragma unroll
    for (int j = 0; j < 8; ++j) r[j] = f2bf(src[j * 128]);
    *(us8*)(wsW + (size_t)t * 8) = r;
  } else if (t < 66048) {
    int u = t - 65536;
    int lane = u & 63, cs = u >> 6;
    int q = lane >> 4, l15 = lane & 15;
    const float* src = V + l15 * 256 + cs * 32 + q * 8;
    us8 r;
#pragma unroll
    for (int j = 0; j < 8; ++j) r[j] = f2bf(src[j]);
    *(us8*)(wsV + (size_t)u * 8) = r;
  }
}

// ---------------- main ----------------
__global__ __launch_bounds__(256, 2) void ntn_main(
    const float* __restrict__ x1, const float* __restrict__ x2,
    const float* __restrict__ b,
    const unsigned short* __restrict__ wsW, const unsigned short* __restrict__ wsV,
    float* __restrict__ out) {
  __shared__ uint4 ldsW[2][2048];   // two 32KB chunk slots = 64KB

  const int tid = threadIdx.x;
  const int lane = tid & 63, wave = tid >> 6;
  const int q = lane >> 4, l15 = lane & 15;
  const int kh = blockIdx.x & 1;          // k range [8kh, 8kh+8)
  const int rb = blockIdx.x >> 1;         // 128-row group
  const int rowbase = rb * 128 + wave * 32;

  const f32x4 zero4 = {0.f, 0.f, 0.f, 0.f};

  // async stage of one 32KB chunk into an LDS slot (8 glds x 64 lanes x 16B / wave)
  auto stage = [&](int cc, int slot) {
    const unsigned short* src = wsW + (size_t)cc * 16384 + (size_t)(wave * 512 + lane) * 8;
    uint4* dst = &ldsW[slot][wave * 512];
#pragma unroll
    for (int i = 0; i < 8; ++i)
      __builtin_amdgcn_global_load_lds(
          (__attribute__((address_space(1))) void*)(void*)(src + i * 512),
          (__attribute__((address_space(3))) void*)(dst + i * 64), 16, 0, 0);
  };

  stage(kh * 16, 0);   // first chunk of our k range

  // ---- X fragments (B-operand), bf16, k-invariant, in registers ----
  // frag[j] = X[row = rowbase + nt*16 + (lane&15)][d = s*32 + (lane>>4)*8 + j]
  bf16x8 xb[2][2][4];
#pragma unroll
  for (int side = 0; side < 2; ++side) {
    const float* xp0 = side ? x2 : x1;
#pragma unroll
    for (int nt = 0; nt < 2; ++nt) {
#pragma unroll
      for (int s = 0; s < 4; ++s) {
        const float* p = xp0 + (size_t)(rowbase + nt * 16 + l15) * 128 + s * 32 + q * 8;
        float4 v0 = *(const float4*)p;
        float4 v1 = *(const float4*)(p + 4);
        us8 uu;
        uu[0] = f2bf(v0.x); uu[1] = f2bf(v0.y); uu[2] = f2bf(v0.z); uu[3] = f2bf(v0.w);
        uu[4] = f2bf(v1.x); uu[5] = f2bf(v1.y); uu[6] = f2bf(v1.z); uu[7] = f2bf(v1.w);
        xb[side][nt][s] = as_bf(uu);
      }
    }
  }

  // ---- part2 + b via MFMA (A = V frags: M=k; B = X frags), kept in registers ----
  f32x4 accP[2];
  {
    bf16x8 vf[8];
#pragma unroll
    for (int cs = 0; cs < 8; ++cs)
      vf[cs] = as_bf(*(const us8*)(wsV + (size_t)(cs * 64 + lane) * 8));
    float4 bv = *(const float4*)(b + q * 4);
#pragma unroll
    for (int nt = 0; nt < 2; ++nt) {
      f32x4 a = zero4;
#pragma unroll
      for (int cs = 0; cs < 8; ++cs)
        a = __builtin_amdgcn_mfma_f32_16x16x32_bf16(vf[cs], xb[cs >> 2][nt][cs & 3], a, 0, 0, 0);
      a.x += bv.x; a.y += bv.y; a.z += bv.z; a.w += bv.w;
      accP[nt] = a;   // lane quad q holds part2+b for k = q*4 + reg
    }
  }

  float nm[2] = {0.f, 0.f}, q1[2] = {0.f, 0.f}, q2[2] = {0.f, 0.f};

  // compute one e-half (4 e-tiles, both sides) from an LDS slot, fold reductions
  auto compute = [&](int slot) {
#pragma unroll
    for (int et = 0; et < 4; ++et) {
      bf16x8 wa[4], wb[4];
#pragma unroll
      for (int s = 0; s < 4; ++s) {
        wa[s] = as_bf(*(const us8*)&ldsW[slot][et * 256 + s * 64 + lane]);
        wb[s] = as_bf(*(const us8*)&ldsW[slot][1024 + et * 256 + s * 64 + lane]);
      }
#pragma unroll
      for (int nt = 0; nt < 2; ++nt) {
        f32x4 a1 = zero4, a2 = zero4;
#pragma unroll
        for (int s = 0; s < 4; ++s)
          a1 = __builtin_amdgcn_mfma_f32_16x16x32_bf16(wa[s], xb[0][nt][s], a1, 0, 0, 0);
#pragma unroll
        for (int s = 0; s < 4; ++s)
          a2 = __builtin_amdgcn_mfma_f32_16x16x32_bf16(wb[s], xb[1][nt][s], a2, 0, 0, 0);
        nm[nt] += a1.x * a2.x + a1.y * a2.y + a1.z * a2.z + a1.w * a2.w;
        q1[nt] += a1.x * a1.x + a1.y * a1.y + a1.z * a1.z + a1.w * a1.w;
        q2[nt] += a2.x * a2.x + a2.y * a2.y + a2.z * a2.z + a2.w * a2.w;
      }
    }
  };

#pragma unroll 1
  for (int kk = 0; kk < 8; ++kk) {
    const int cbase = kh * 16 + 2 * kk;
    __syncthreads();                       // chunk (kk, h=0) in slot0; slot1 free
    stage(cbase + 1, 1);
    compute(0);
    __syncthreads();                       // chunk (kk, h=1) in slot1; slot0 free
    if (kk < 7) stage(cbase + 2, 0);
    compute(1);

    const int k = kh * 8 + kk;
    const int qo = k >> 2;                 // owning lane quad
    const int r  = k & 3;
#pragma unroll
    for (int nt = 0; nt < 2; ++nt) {
      float n = nm[nt], s1 = q1[nt], s2 = q2[nt];
      n  += __shfl_xor(n, 16);  n  += __shfl_xor(n, 32);
      s1 += __shfl_xor(s1, 16); s1 += __shfl_xor(s1, 32);
      s2 += __shfl_xor(s2, 16); s2 += __shfl_xor(s2, 32);
      float d1 = fmaxf(sqrtf(s1), 1e-8f);
      float d2 = fmaxf(sqrtf(s2), 1e-8f);
      float p1 = n / (d1 * d2);
      float pc = (r == 0) ? accP[nt].x : (r == 1) ? accP[nt].y
               : (r == 2) ? accP[nt].z : accP[nt].w;
      if (q == qo)
        out[(size_t)(rowbase + nt * 16 + l15) * 16 + k] = fmaxf(p1 + pc, 0.f);
      nm[nt] = 0.f; q1[nt] = 0.f; q2[nt] = 0.f;
    }
  }
}

extern "C" void kernel_launch(void* const* d_in, const int* in_sizes, int n_in,
                              void* d_out, int out_size, void* d_ws, size_t ws_size,
                              hipStream_t stream) {
  const float* x1 = (const float*)d_in[0];
  const float* x2 = (const float*)d_in[1];
  const float* W1 = (const float*)d_in[2];
  const float* W2 = (const float*)d_in[3];
  const float* V  = (const float*)d_in[4];
  const float* b  = (const float*)d_in[5];
  float* out = (float*)d_out;
  unsigned short* wsW = (unsigned short*)d_ws;
  unsigned short* wsV = wsW + (size_t)65536 * 8;   // 1MB offset

  ntn_prep<<<258, 256, 0, stream>>>(W1, W2, V, wsW, wsV);
  ntn_main<<<512, 256, 0, stream>>>(x1, x2, b, wsW, wsV, out);
}